// Round 20
// baseline (1181.991 us; speedup 1.0000x reference)
//
#include <hip/hip_runtime.h>
#include <stdint.h>

// MoE: E=8 routed (top-2) + 2 shared experts, H=2048, I=5120, T=2048 tokens.
// Sparse expert compute in bf16 MFMA (16x16x32), fp32 router.
// R20: gateup split into k_gate + k_up: each 256x128@512thr single-acc
//      (per-wave 64x64, 64 acc regs), 48KB LDS -> 2 blocks/CU overlap at
//      CONSTANT weight traffic (de-confounds R19). g staged bf16 in the h
//      buffer (k_up reads + overwrites in place). down/combine = R18.

#define E_ 8
#define H_ 2048
#define I_ 5120
#define T_ 2048
#define NSLOT 10           // 8 routed + 2 shared

typedef __attribute__((ext_vector_type(4))) float f32x4;
typedef __attribute__((ext_vector_type(8))) __bf16 bf16x8;
typedef __attribute__((ext_vector_type(4))) unsigned int u32x4;
typedef __attribute__((ext_vector_type(2))) unsigned int u32x2;

__device__ __forceinline__ int sw(int r) { return (r ^ (r >> 2)) & 3; }

typedef __attribute__((address_space(1))) const void* gptr1_t;
typedef __attribute__((address_space(3))) void* lptr3_t;
__device__ __forceinline__ void load_lds16(const void* g, void* l) {
  __builtin_amdgcn_global_load_lds((gptr1_t)g, (lptr3_t)l, 16, 0, 0);
}

// barrier draining prev body's vmem (leave newest N in flight) + LDS writes
#define PIPE_SYNC(N)                                                    \
  do {                                                                  \
    asm volatile("s_waitcnt vmcnt(" #N ") lgkmcnt(0)" ::: "memory");    \
    __builtin_amdgcn_sched_barrier(0);                                  \
    __builtin_amdgcn_s_barrier();                                       \
    __builtin_amdgcn_sched_barrier(0);                                  \
  } while (0)

__device__ __forceinline__ unsigned short f2bf(float f) {
  unsigned u = __builtin_bit_cast(unsigned, f);
  u += 0x7FFFu + ((u >> 16) & 1u);   // round-to-nearest-even
  return (unsigned short)(u >> 16);
}

__device__ __forceinline__ float bf2f(unsigned short v) {
  unsigned u = (unsigned)v << 16;
  return __builtin_bit_cast(float, u);
}

// 4 fp32 -> 4 bf16 (RNE) packed in u32x2 via v_cvt_pk_bf16_f32
__device__ __forceinline__ u32x2 cvt4(f32x4 v) {
  unsigned r0, r1;
  asm("v_cvt_pk_bf16_f32 %0, %1, %2" : "=v"(r0) : "v"(v[0]), "v"(v[1]));
  asm("v_cvt_pk_bf16_f32 %0, %1, %2" : "=v"(r1) : "v"(v[2]), "v"(v[3]));
  u32x2 w; w[0] = r0; w[1] = r1;
  return w;
}

// ---------------- x fp32 -> bf16 pre-cast (RNE, same as staging did) --------
__global__ __launch_bounds__(256) void k_castx(const float* __restrict__ x,
                                               unsigned short* __restrict__ xb) {
  const int i = (blockIdx.x * 256 + threadIdx.x) * 8;
  f32x4 a = *(const f32x4*)(x + i);
  f32x4 b = *(const f32x4*)(x + i + 4);
  u32x2 lo = cvt4(a), hi = cvt4(b);
  u32x4 o; o[0] = lo[0]; o[1] = lo[1]; o[2] = hi[0]; o[3] = hi[1];
  *(u32x4*)(xb + i) = o;
}

// ---------------- router: fp32 logits, sigmoid, top-2, renormalize ----------
__global__ __launch_bounds__(64) void k_router(const float* __restrict__ x,
                                               const float* __restrict__ wr,
                                               int* __restrict__ tki,
                                               float* __restrict__ tkw) {
  const int t = blockIdx.x, lane = threadIdx.x;
  const float* xr = x + (size_t)t * H_;
  float lg[E_];
#pragma unroll
  for (int e = 0; e < E_; ++e) {
    const float* w = wr + (size_t)e * H_;
    float acc = 0.f;
    for (int k = lane; k < H_; k += 64) acc += xr[k] * w[k];
#pragma unroll
    for (int off = 32; off > 0; off >>= 1) acc += __shfl_down(acc, off);
    lg[e] = acc;  // valid on lane 0
  }
  if (lane == 0) {
    float sc[E_];
#pragma unroll
    for (int e = 0; e < E_; ++e) sc[e] = 1.f / (1.f + expf(-lg[e]));
    int b0 = 0;
#pragma unroll
    for (int e = 1; e < E_; ++e) if (sc[e] > sc[b0]) b0 = e;
    int b1 = -1;
#pragma unroll
    for (int e = 0; e < E_; ++e) {
      if (e == b0) continue;
      if (b1 < 0 || sc[e] > sc[b1]) b1 = e;
    }
    float s0 = sc[b0], s1 = sc[b1], inv = 1.f / (s0 + s1);
    tki[2 * t] = b0; tki[2 * t + 1] = b1;
    tkw[2 * t] = s0 * inv; tkw[2 * t + 1] = s1 * inv;
  }
}

// ------- per-slot token lists (compaction) + inverse map, shared = identity -
__global__ __launch_bounds__(64) void k_lists(const int* __restrict__ tki,
                                              const float* __restrict__ tkw,
                                              int* __restrict__ elist,
                                              float* __restrict__ ew,
                                              int* __restrict__ ecnt,
                                              int* __restrict__ ipos) {
  const int s = blockIdx.x, lane = threadIdx.x;
  if (s < E_) {
    int base = 0;
    for (int c = 0; c < T_ / 64; ++c) {
      int t = c * 64 + lane;
      int i0 = tki[2 * t], i1 = tki[2 * t + 1];
      int flag = (i0 == s) ? 1 : ((i1 == s) ? 2 : 0);
      unsigned long long m = __ballot(flag != 0);
      int pre = __popcll(m & ((1ull << lane) - 1ull));
      if (flag) {
        elist[s * T_ + base + pre] = t;
        ew[s * T_ + base + pre] = tkw[2 * t + flag - 1];
        ipos[2 * t + flag - 1] = base + pre;   // position within slot list
      }
      base += __popcll(m);
    }
    int padded = (base + 255) & ~255;
    for (int p = base + lane; p < padded; p += 64) { elist[s * T_ + p] = 0; ew[s * T_ + p] = 0.f; }
    if (lane == 0) ecnt[s] = base;
  } else {
    for (int i = lane; i < T_; i += 64) { elist[s * T_ + i] = i; ew[s * T_ + i] = 1.f; }
    if (lane == 0) ecnt[s] = T_;
  }
}

__global__ void k_bases(const int* __restrict__ ecnt, int* __restrict__ sbase) {
  if (threadIdx.x == 0 && blockIdx.x == 0) {
    int b = 0;
    for (int s = 0; s < NSLOT; ++s) { sbase[s] = b; b += (ecnt[s] + 255) & ~255; }
  }
}

// -------- gate GEMM: g = x.wg^T, bf16 -> h buffer (staging for k_up) --------
// tile 256(tok) x 128(I) x BK=32 over K=H; 512 thr, 8 waves (4r x 2c);
// per-wave 64x64 single acc. Dbuf swizzled LDS (48KB), 2 blocks/CU.
__global__ __launch_bounds__(512, 4) void k_gate(
    const unsigned short* __restrict__ xb,
    const float* __restrict__ wg_all, const float* __restrict__ sg_all,
    const int* __restrict__ elist, const int* __restrict__ ecnt,
    const int* __restrict__ sbase, unsigned short* __restrict__ h) {
  const int s = blockIdx.z;
  const int cnt = ecnt[s];
  const int r0 = blockIdx.y * 256;
  if (r0 >= cnt) return;
  const int n0 = blockIdx.x * 128;
  const float* bw = (s < E_) ? wg_all + (size_t)s * I_ * H_
                             : sg_all + (size_t)(s - E_) * I_ * H_;
  const int* lst = elist + s * T_;
  const int hrow0 = sbase[s] + r0;

  __shared__ u32x4 sA[2][1024];   // 256 rows x 4 chunks (32KB)
  __shared__ u32x4 sB[2][512];    // 128 rows x 4 chunks (16KB)

  const int tid = threadIdx.x;
  const int wv = tid >> 6, lane = tid & 63;
  const int wr = wv >> 1, wc = wv & 1;
  const int fr = lane & 15, k8 = lane >> 4;

  // A staging: 2 chunks (32B) per thread, gathered token rows
  const int ar = tid >> 1, ca2 = (tid & 1) * 2;
  int li = r0 + ar; if (li >= cnt) li = r0;   // clamp; masked downstream
  const unsigned short* xp = xb + (size_t)lst[li] * H_ + ca2 * 8;
  // B staging: one 16B chunk (8 fp32 -> bf16) per thread
  const int brr = tid >> 2, cb = tid & 3;
  const float* bp = bw + (size_t)(n0 + brr) * H_ + cb * 8;

  u32x4 ra0, ra1; f32x4 rb0, rb1;

  f32x4 acc[4][4];
#pragma unroll
  for (int m = 0; m < 4; ++m)
#pragma unroll
    for (int n = 0; n < 4; ++n) acc[m][n] = (f32x4){0.f, 0.f, 0.f, 0.f};

  auto loadNext = [&]() {
    ra0 = *(const u32x4*)xp; ra1 = *(const u32x4*)(xp + 8); xp += 32;
    rb0 = *(const f32x4*)bp; rb1 = *(const f32x4*)(bp + 4); bp += 32;
  };
  auto stage = [&](int b) {
    sA[b][ar * 4 + (ca2 ^ sw(ar))] = ra0;
    sA[b][ar * 4 + ((ca2 + 1) ^ sw(ar))] = ra1;
    u32x2 lo = cvt4(rb0), hi = cvt4(rb1);
    u32x4 q; q[0] = lo[0]; q[1] = lo[1]; q[2] = hi[0]; q[3] = hi[1];
    sB[b][brr * 4 + (cb ^ sw(brr))] = q;
  };
  auto compute = [&](int b) {
    bf16x8 af[4], bf[4];
#pragma unroll
    for (int m = 0; m < 4; ++m) {
      int r = wr * 64 + m * 16 + fr;
      af[m] = __builtin_bit_cast(bf16x8, sA[b][r * 4 + (k8 ^ sw(r))]);
    }
#pragma unroll
    for (int n = 0; n < 4; ++n) {
      int r = wc * 64 + n * 16 + fr;
      bf[n] = __builtin_bit_cast(bf16x8, sB[b][r * 4 + (k8 ^ sw(r))]);
    }
#pragma unroll
    for (int m = 0; m < 4; ++m)
#pragma unroll
      for (int n = 0; n < 4; ++n)
        acc[m][n] = __builtin_amdgcn_mfma_f32_16x16x32_bf16(af[m], bf[n], acc[m][n], 0, 0, 0);
  };

  const int KT = H_ / 32;  // 64
  loadNext();              // kt=0
  stage(0);
  loadNext();              // kt=1 in flight
  __syncthreads();
  int cur = 0;
  for (int kt = 0; kt < KT; ++kt) {
    compute(cur);
    if (kt + 1 < KT) {
      stage(cur ^ 1);
      if (kt + 2 < KT) loadNext();  // issue BEFORE barrier (R9 schedule)
      __syncthreads();
      cur ^= 1;
    }
  }

  // epilogue: store raw gate values bf16 into h (k_up consumes in place)
#pragma unroll
  for (int m = 0; m < 4; ++m)
#pragma unroll
    for (int r = 0; r < 4; ++r) {
      int rit = wr * 64 + m * 16 + k8 * 4 + r;
      unsigned short* grow = h + (size_t)(hrow0 + rit) * I_ + n0 + wc * 64 + fr;
#pragma unroll
      for (int n = 0; n < 4; ++n) grow[n * 16] = f2bf(acc[m][n][r]);
    }
}

// -------- up GEMM: h = ew * silu(g) * (x.wu^T), in-place over g ------------
__global__ __launch_bounds__(512, 4) void k_up(
    const unsigned short* __restrict__ xb,
    const float* __restrict__ wu_all, const float* __restrict__ su_all,
    const int* __restrict__ elist, const float* __restrict__ ew,
    const int* __restrict__ ecnt,
    const int* __restrict__ sbase, unsigned short* __restrict__ h) {
  const int s = blockIdx.z;
  const int cnt = ecnt[s];
  const int r0 = blockIdx.y * 256;
  if (r0 >= cnt) return;
  const int n0 = blockIdx.x * 128;
  const float* bw = (s < E_) ? wu_all + (size_t)s * I_ * H_
                             : su_all + (size_t)(s - E_) * I_ * H_;
  const int* lst = elist + s * T_;
  const int hrow0 = sbase[s] + r0;

  __shared__ u32x4 sA[2][1024];
  __shared__ u32x4 sB[2][512];

  const int tid = threadIdx.x;
  const int wv = tid >> 6, lane = tid & 63;
  const int wr = wv >> 1, wc = wv & 1;
  const int fr = lane & 15, k8 = lane >> 4;

  const int ar = tid >> 1, ca2 = (tid & 1) * 2;
  int li = r0 + ar; if (li >= cnt) li = r0;
  const unsigned short* xp = xb + (size_t)lst[li] * H_ + ca2 * 8;
  const int brr = tid >> 2, cb = tid & 3;
  const float* bp = bw + (size_t)(n0 + brr) * H_ + cb * 8;

  u32x4 ra0, ra1; f32x4 rb0, rb1;

  f32x4 acc[4][4];
#pragma unroll
  for (int m = 0; m < 4; ++m)
#pragma unroll
    for (int n = 0; n < 4; ++n) acc[m][n] = (f32x4){0.f, 0.f, 0.f, 0.f};

  auto loadNext = [&]() {
    ra0 = *(const u32x4*)xp; ra1 = *(const u32x4*)(xp + 8); xp += 32;
    rb0 = *(const f32x4*)bp; rb1 = *(const f32x4*)(bp + 4); bp += 32;
  };
  auto stage = [&](int b) {
    sA[b][ar * 4 + (ca2 ^ sw(ar))] = ra0;
    sA[b][ar * 4 + ((ca2 + 1) ^ sw(ar))] = ra1;
    u32x2 lo = cvt4(rb0), hi = cvt4(rb1);
    u32x4 q; q[0] = lo[0]; q[1] = lo[1]; q[2] = hi[0]; q[3] = hi[1];
    sB[b][brr * 4 + (cb ^ sw(brr))] = q;
  };
  auto compute = [&](int b) {
    bf16x8 af[4], bf[4];
#pragma unroll
    for (int m = 0; m < 4; ++m) {
      int r = wr * 64 + m * 16 + fr;
      af[m] = __builtin_bit_cast(bf16x8, sA[b][r * 4 + (k8 ^ sw(r))]);
    }
#pragma unroll
    for (int n = 0; n < 4; ++n) {
      int r = wc * 64 + n * 16 + fr;
      bf[n] = __builtin_bit_cast(bf16x8, sB[b][r * 4 + (k8 ^ sw(r))]);
    }
#pragma unroll
    for (int m = 0; m < 4; ++m)
#pragma unroll
      for (int n = 0; n < 4; ++n)
        acc[m][n] = __builtin_amdgcn_mfma_f32_16x16x32_bf16(af[m], bf[n], acc[m][n], 0, 0, 0);
  };

  const int KT = H_ / 32;  // 64
  loadNext();
  stage(0);
  loadNext();
  __syncthreads();
  int cur = 0;
  for (int kt = 0; kt < KT; ++kt) {
    compute(cur);
    if (kt + 1 < KT) {
      stage(cur ^ 1);
      if (kt + 2 < KT) loadNext();
      __syncthreads();
      cur ^= 1;
    }
  }

  // epilogue: read g (bf16, written by k_gate), h = ew * silu(g) * u
#pragma unroll
  for (int m = 0; m < 4; ++m)
#pragma unroll
    for (int r = 0; r < 4; ++r) {
      int rit = wr * 64 + m * 16 + k8 * 4 + r;
      if (r0 + rit < cnt) {
        float wgt = ew[s * T_ + r0 + rit];
        unsigned short* hrow = h + (size_t)(hrow0 + rit) * I_ + n0 + wc * 64 + fr;
#pragma unroll
        for (int n = 0; n < 4; ++n) {
          float g = bf2f(hrow[n * 16]);
          float hv = g / (1.f + expf(-g)) * acc[m][n][r] * wgt;
          hrow[n * 16] = f2bf(hv);
        }
      }
    }
}

// -------- down GEMM: y[srow] = h . wd^T (plain stores) or atomic to out ----
// == R18 verbatim == A: tri-buffered DMA; B: reg+cvt dbuf; counted vmcnt.
__global__ __launch_bounds__(512, 4) void k_down(
    const unsigned short* __restrict__ h,
    const float* __restrict__ wd_all, const float* __restrict__ sd_all,
    const int* __restrict__ elist,
    const int* __restrict__ ecnt, const int* __restrict__ sbase,
    float* __restrict__ y, int use_y,
    float* __restrict__ out) {
  const int s = blockIdx.z;
  const int cnt = ecnt[s];
  const int r0 = blockIdx.y * 256;
  if (r0 >= cnt) return;
  const int n0 = blockIdx.x * 128;
  const float* bw = (s < E_) ? wd_all + (size_t)s * H_ * I_
                             : sd_all + (size_t)(s - E_) * H_ * I_;
  const int hrow0 = sbase[s] + r0;

  __shared__ u32x4 sA[3][1024];   // 256 rows x 4 chunks, tri (48KB)
  __shared__ u32x4 sB[2][512];    // 128 rows x 4 chunks, dbuf (16KB)

  const int tid = threadIdx.x;
  const int wv = tid >> 6, lane = tid & 63;
  const int wr = wv >> 1, wc = wv & 1;
  const int fr = lane & 15, k8 = lane >> 4;

  const int arow0 = wv * 32 + (lane >> 2);
  const int arow1 = arow0 + 16;
  const unsigned short* aSrc0 =
      h + (size_t)(hrow0 + arow0) * I_ + (((lane & 3) ^ sw(arow0)) * 8);
  const unsigned short* aSrc1 =
      h + (size_t)(hrow0 + arow1) * I_ + (((lane & 3) ^ sw(arow1)) * 8);

  const int brr = tid >> 2, cb = tid & 3;
  const float* bp = bw + (size_t)(n0 + brr) * I_ + cb * 8;
  f32x4 rb0, rb1;

  f32x4 acc[4][4];
#pragma unroll
  for (int m = 0; m < 4; ++m)
#pragma unroll
    for (int n = 0; n < 4; ++n) acc[m][n] = (f32x4){0.f, 0.f, 0.f, 0.f};

  auto dmaA = [&](int b, int kt) {
    load_lds16(aSrc0 + kt * 32, &sA[b][wv * 128]);
    load_lds16(aSrc1 + kt * 32, &sA[b][wv * 128 + 64]);
  };
  auto loadB = [&]() {
    rb0 = *(const f32x4*)bp; rb1 = *(const f32x4*)(bp + 4); bp += 32;
  };
  auto stageB = [&](int b) {
    u32x2 lo = cvt4(rb0), hi = cvt4(rb1);
    u32x4 q; q[0] = lo[0]; q[1] = lo[1]; q[2] = hi[0]; q[3] = hi[1];
    sB[b][brr * 4 + (cb ^ sw(brr))] = q;
  };
  auto compute = [&](int a, int b) {
    bf16x8 af[4], bf[4];
#pragma unroll
    for (int m = 0; m < 4; ++m) {
      int r = wr * 64 + m * 16 + fr;
      af[m] = __builtin_bit_cast(bf16x8, sA[a][r * 4 + (k8 ^ sw(r))]);
    }
#pragma unroll
    for (int n = 0; n < 4; ++n) {
      int r = wc * 64 + n * 16 + fr;
      bf[n] = __builtin_bit_cast(bf16x8, sB[b][r * 4 + (k8 ^ sw(r))]);
    }
#pragma unroll
    for (int m = 0; m < 4; ++m)
#pragma unroll
      for (int n = 0; n < 4; ++n)
        acc[m][n] = __builtin_amdgcn_mfma_f32_16x16x32_bf16(af[m], bf[n], acc[m][n], 0, 0, 0);
  };

  const int KT = I_ / 32;  // 160
  loadB();
  dmaA(0, 0);
  stageB(0);
  loadB();
  dmaA(1, 1);
  PIPE_SYNC(4);
  int aCur = 0, bCur = 0;
  for (int kt = 0; kt < KT; ++kt) {
    compute(aCur, bCur);
    if (kt + 1 < KT) {
      stageB(bCur ^ 1);
      if (kt + 2 < KT) {
        int nx = aCur + 2; if (nx >= 3) nx -= 3;
        dmaA(nx, kt + 2);
        loadB();
        PIPE_SYNC(4);
      } else {
        PIPE_SYNC(0);
      }
      aCur = (aCur == 2) ? 0 : aCur + 1;
      bCur ^= 1;
    }
  }

  if (use_y) {
#pragma unroll
    for (int m = 0; m < 4; ++m)
#pragma unroll
      for (int r = 0; r < 4; ++r) {
        int rit = wr * 64 + m * 16 + k8 * 4 + r;
        float* yrow = y + (size_t)(hrow0 + rit) * H_ + n0 + wc * 64 + fr;
#pragma unroll
        for (int n = 0; n < 4; ++n) yrow[n * 16] = acc[m][n][r];
      }
  } else {
    const int* lst = elist + s * T_;
#pragma unroll
    for (int m = 0; m < 4; ++m)
#pragma unroll
      for (int r = 0; r < 4; ++r) {
        int rit = wr * 64 + m * 16 + k8 * 4 + r;
        if (r0 + rit < cnt) {
          int t = lst[r0 + rit];
          float* orow = out + (size_t)t * H_ + n0 + wc * 64 + fr;
#pragma unroll
          for (int n = 0; n < 4; ++n) atomicAdd(orow + n * 16, acc[m][n][r]);
        }
      }
  }
}

// -------- combine: out[t] = y[routed0] + y[routed1] + y[shared0] + y[shared1]
__global__ __launch_bounds__(256) void k_combine(
    const float* __restrict__ y, const int* __restrict__ tki,
    const int* __restrict__ ipos, const int* __restrict__ sbase,
    float* __restrict__ out) {
  const int t = blockIdx.x;
  const int c = threadIdx.x * 8;
  const size_t r0 = (size_t)(sbase[tki[2 * t]] + ipos[2 * t]) * H_ + c;
  const size_t r1 = (size_t)(sbase[tki[2 * t + 1]] + ipos[2 * t + 1]) * H_ + c;
  const size_t r2 = (size_t)(sbase[8] + t) * H_ + c;
  const size_t r3 = (size_t)(sbase[9] + t) * H_ + c;
  f32x4 a0 = *(const f32x4*)(y + r0), b0 = *(const f32x4*)(y + r0 + 4);
  f32x4 a1 = *(const f32x4*)(y + r1), b1 = *(const f32x4*)(y + r1 + 4);
  f32x4 a2 = *(const f32x4*)(y + r2), b2 = *(const f32x4*)(y + r2 + 4);
  f32x4 a3 = *(const f32x4*)(y + r3), b3 = *(const f32x4*)(y + r3 + 4);
  f32x4 sa = (a0 + a1) + (a2 + a3);
  f32x4 sb = (b0 + b1) + (b2 + b3);
  float* o = out + (size_t)t * H_ + c;
  *(f32x4*)o = sa;
  *(f32x4*)(o + 4) = sb;
}

extern "C" void kernel_launch(void* const* d_in, const int* in_sizes, int n_in,
                              void* d_out, int out_size, void* d_ws, size_t ws_size,
                              hipStream_t stream) {
  const float* x  = (const float*)d_in[0];
  const float* wr = (const float*)d_in[1];
  const float* wg = (const float*)d_in[2];
  const float* wu = (const float*)d_in[3];
  const float* wd = (const float*)d_in[4];
  const float* sg = (const float*)d_in[5];
  const float* su = (const float*)d_in[6];
  const float* sd = (const float*)d_in[7];
  float* out = (float*)d_out;
  char* ws = (char*)d_ws;

  // workspace layout
  int*   tki   = (int*)(ws);                 // T*2 ints
  float* tkw   = (float*)(ws + 16384);       // T*2 floats
  int*   elist = (int*)(ws + 32768);         // NSLOT*T ints
  float* ew    = (float*)(ws + 114688);      // NSLOT*T floats
  int*   ecnt  = (int*)(ws + 196608);        // NSLOT ints
  int*   sbase = (int*)(ws + 196864);        // NSLOT ints
  int*   ipos  = (int*)(ws + 197632);        // T*2 ints
  unsigned short* xb = (unsigned short*)(ws + 262144);            // 8.4 MB
  unsigned short* h  = (unsigned short*)(ws + 262144 + 8388608);  // <=10496 rows x I bf16 (107.5 MB)
  float* y = (float*)(ws + 262144 + 8388608 + 107479040);         // <=10496 rows x H fp32 (86 MB)
  const size_t ws_need_y = 262144ull + 8388608ull + 107479040ull + 85983232ull;
  const int use_y = (ws_size >= ws_need_y) ? 1 : 0;

  k_castx<<<T_ * H_ / (256 * 8), 256, 0, stream>>>(x, xb);
  k_router<<<T_, 64, 0, stream>>>(x, wr, tki, tkw);
  k_lists<<<NSLOT, 64, 0, stream>>>(tki, tkw, elist, ew, ecnt, ipos);
  k_bases<<<1, 1, 0, stream>>>(ecnt, sbase);
  k_gate<<<dim3(I_ / 128, T_ / 256, NSLOT), 512, 0, stream>>>(
      xb, wg, sg, elist, ecnt, sbase, h);
  k_up<<<dim3(I_ / 128, T_ / 256, NSLOT), 512, 0, stream>>>(
      xb, wu, su, elist, ew, ecnt, sbase, h);
  if (!use_y) hipMemsetAsync(out, 0, (size_t)T_ * H_ * sizeof(float), stream);
  k_down<<<dim3(H_ / 128, T_ / 256, NSLOT), 512, 0, stream>>>(
      h, wd, sd, elist, ecnt, sbase, y, use_y, out);
  if (use_y)
    k_combine<<<T_, 256, 0, stream>>>(y, tki, ipos, sbase, out);
}

// Round 21
// 963.077 us; speedup vs baseline: 1.2273x; 1.2273x over previous
//
#include <hip/hip_runtime.h>
#include <stdint.h>

// MoE: E=8 routed (top-2) + 2 shared experts, H=2048, I=5120, T=2048 tokens.
// Sparse expert compute in bf16 MFMA (16x16x32), fp32 router.
// R21: composition of measured bests. gateup = R13/R16 fused 1024-thr
//      reg-staged (best: ~490us). down = R18 A-DMA tri-buffer + counted
//      vmcnt (best: ~374us). Epilogue = R17 y-stores + k_combine (no
//      atomics). All kernels verbatim from passing rounds.

#define E_ 8
#define H_ 2048
#define I_ 5120
#define T_ 2048
#define NSLOT 10           // 8 routed + 2 shared

typedef __attribute__((ext_vector_type(4))) float f32x4;
typedef __attribute__((ext_vector_type(8))) __bf16 bf16x8;
typedef __attribute__((ext_vector_type(4))) unsigned int u32x4;
typedef __attribute__((ext_vector_type(2))) unsigned int u32x2;

__device__ __forceinline__ int sw(int r) { return (r ^ (r >> 2)) & 3; }

typedef __attribute__((address_space(1))) const void* gptr1_t;
typedef __attribute__((address_space(3))) void* lptr3_t;
__device__ __forceinline__ void load_lds16(const void* g, void* l) {
  __builtin_amdgcn_global_load_lds((gptr1_t)g, (lptr3_t)l, 16, 0, 0);
}

// barrier draining prev body's vmem (leave newest N in flight) + LDS writes
#define PIPE_SYNC(N)                                                    \
  do {                                                                  \
    asm volatile("s_waitcnt vmcnt(" #N ") lgkmcnt(0)" ::: "memory");    \
    __builtin_amdgcn_sched_barrier(0);                                  \
    __builtin_amdgcn_s_barrier();                                       \
    __builtin_amdgcn_sched_barrier(0);                                  \
  } while (0)

__device__ __forceinline__ unsigned short f2bf(float f) {
  unsigned u = __builtin_bit_cast(unsigned, f);
  u += 0x7FFFu + ((u >> 16) & 1u);   // round-to-nearest-even
  return (unsigned short)(u >> 16);
}

// 4 fp32 -> 4 bf16 (RNE) packed in u32x2 via v_cvt_pk_bf16_f32
__device__ __forceinline__ u32x2 cvt4(f32x4 v) {
  unsigned r0, r1;
  asm("v_cvt_pk_bf16_f32 %0, %1, %2" : "=v"(r0) : "v"(v[0]), "v"(v[1]));
  asm("v_cvt_pk_bf16_f32 %0, %1, %2" : "=v"(r1) : "v"(v[2]), "v"(v[3]));
  u32x2 w; w[0] = r0; w[1] = r1;
  return w;
}

// ---------------- x fp32 -> bf16 pre-cast (RNE, same as staging did) --------
__global__ __launch_bounds__(256) void k_castx(const float* __restrict__ x,
                                               unsigned short* __restrict__ xb) {
  const int i = (blockIdx.x * 256 + threadIdx.x) * 8;
  f32x4 a = *(const f32x4*)(x + i);
  f32x4 b = *(const f32x4*)(x + i + 4);
  u32x2 lo = cvt4(a), hi = cvt4(b);
  u32x4 o; o[0] = lo[0]; o[1] = lo[1]; o[2] = hi[0]; o[3] = hi[1];
  *(u32x4*)(xb + i) = o;
}

// ---------------- router: fp32 logits, sigmoid, top-2, renormalize ----------
__global__ __launch_bounds__(64) void k_router(const float* __restrict__ x,
                                               const float* __restrict__ wr,
                                               int* __restrict__ tki,
                                               float* __restrict__ tkw) {
  const int t = blockIdx.x, lane = threadIdx.x;
  const float* xr = x + (size_t)t * H_;
  float lg[E_];
#pragma unroll
  for (int e = 0; e < E_; ++e) {
    const float* w = wr + (size_t)e * H_;
    float acc = 0.f;
    for (int k = lane; k < H_; k += 64) acc += xr[k] * w[k];
#pragma unroll
    for (int off = 32; off > 0; off >>= 1) acc += __shfl_down(acc, off);
    lg[e] = acc;  // valid on lane 0
  }
  if (lane == 0) {
    float sc[E_];
#pragma unroll
    for (int e = 0; e < E_; ++e) sc[e] = 1.f / (1.f + expf(-lg[e]));
    int b0 = 0;
#pragma unroll
    for (int e = 1; e < E_; ++e) if (sc[e] > sc[b0]) b0 = e;
    int b1 = -1;
#pragma unroll
    for (int e = 0; e < E_; ++e) {
      if (e == b0) continue;
      if (b1 < 0 || sc[e] > sc[b1]) b1 = e;
    }
    float s0 = sc[b0], s1 = sc[b1], inv = 1.f / (s0 + s1);
    tki[2 * t] = b0; tki[2 * t + 1] = b1;
    tkw[2 * t] = s0 * inv; tkw[2 * t + 1] = s1 * inv;
  }
}

// ------- per-slot token lists (compaction) + inverse map, shared = identity -
__global__ __launch_bounds__(64) void k_lists(const int* __restrict__ tki,
                                              const float* __restrict__ tkw,
                                              int* __restrict__ elist,
                                              float* __restrict__ ew,
                                              int* __restrict__ ecnt,
                                              int* __restrict__ ipos) {
  const int s = blockIdx.x, lane = threadIdx.x;
  if (s < E_) {
    int base = 0;
    for (int c = 0; c < T_ / 64; ++c) {
      int t = c * 64 + lane;
      int i0 = tki[2 * t], i1 = tki[2 * t + 1];
      int flag = (i0 == s) ? 1 : ((i1 == s) ? 2 : 0);
      unsigned long long m = __ballot(flag != 0);
      int pre = __popcll(m & ((1ull << lane) - 1ull));
      if (flag) {
        elist[s * T_ + base + pre] = t;
        ew[s * T_ + base + pre] = tkw[2 * t + flag - 1];
        ipos[2 * t + flag - 1] = base + pre;   // position within slot list
      }
      base += __popcll(m);
    }
    int padded = (base + 255) & ~255;
    for (int p = base + lane; p < padded; p += 64) { elist[s * T_ + p] = 0; ew[s * T_ + p] = 0.f; }
    if (lane == 0) ecnt[s] = base;
  } else {
    for (int i = lane; i < T_; i += 64) { elist[s * T_ + i] = i; ew[s * T_ + i] = 1.f; }
    if (lane == 0) ecnt[s] = T_;
  }
}

__global__ void k_bases(const int* __restrict__ ecnt, int* __restrict__ sbase) {
  if (threadIdx.x == 0 && blockIdx.x == 0) {
    int b = 0;
    for (int s = 0; s < NSLOT; ++s) { sbase[s] = b; b += (ecnt[s] + 255) & ~255; }
  }
}

// -------- gate/up GEMM: h = ew * silu(x.wg^T) * (x.wu^T), bf16 out ----------
// == R13 verbatim == tile 256x128xBK32, 16 waves (4r x 4c), dbuf swizzled LDS.
__global__ __launch_bounds__(1024, 4) void k_gateup(
    const unsigned short* __restrict__ xb,
    const float* __restrict__ wg_all, const float* __restrict__ wu_all,
    const float* __restrict__ sg_all, const float* __restrict__ su_all,
    const int* __restrict__ elist, const float* __restrict__ ew,
    const int* __restrict__ ecnt,
    const int* __restrict__ sbase, unsigned short* __restrict__ h) {
  const int s = blockIdx.z;
  const int cnt = ecnt[s];
  const int r0 = blockIdx.y * 256;
  if (r0 >= cnt) return;
  const int n0 = blockIdx.x * 128;
  const float* gw; const float* uw;
  if (s < E_) { gw = wg_all + (size_t)s * I_ * H_; uw = wu_all + (size_t)s * I_ * H_; }
  else        { gw = sg_all + (size_t)(s - E_) * I_ * H_; uw = su_all + (size_t)(s - E_) * I_ * H_; }
  const int* lst = elist + s * T_;
  const int hrow0 = sbase[s] + r0;

  __shared__ u32x4 sA[2][256 * 4];
  __shared__ u32x4 sG[2][128 * 4];
  __shared__ u32x4 sU[2][128 * 4];

  const int tid = threadIdx.x;
  const int w = tid >> 6, lane = tid & 63;
  const int wr = w >> 2, wc = w & 3;
  const int fr = lane & 15, k8 = lane >> 4;

  const int ar = tid >> 2, ca = tid & 3;
  int li = r0 + ar; if (li >= cnt) li = r0;   // clamp: rows >= cnt masked later
  const unsigned short* xp = xb + (size_t)lst[li] * H_ + ca * 8;
  const int br = tid >> 3, cb = (tid & 7) >> 1, bh = tid & 1;
  const float* gp = gw + (size_t)(n0 + br) * H_ + (tid & 7) * 4;
  const float* up = uw + (size_t)(n0 + br) * H_ + (tid & 7) * 4;

  u32x4 ra; f32x4 rg, ru;

  f32x4 accg[4][2], accu[4][2];
#pragma unroll
  for (int m = 0; m < 4; ++m)
#pragma unroll
    for (int n = 0; n < 2; ++n) {
      accg[m][n] = (f32x4){0.f, 0.f, 0.f, 0.f};
      accu[m][n] = (f32x4){0.f, 0.f, 0.f, 0.f};
    }

  auto loadNext = [&]() {
    ra = *(const u32x4*)xp; rg = *(const f32x4*)gp; ru = *(const f32x4*)up;
    xp += 32; gp += 32; up += 32;
  };
  auto stage = [&](int b) {
    sA[b][ar * 4 + (ca ^ sw(ar))] = ra;
    ((u32x2*)&sG[b][br * 4 + (cb ^ sw(br))])[bh] = cvt4(rg);
    ((u32x2*)&sU[b][br * 4 + (cb ^ sw(br))])[bh] = cvt4(ru);
  };
  auto compute = [&](int b) {
    bf16x8 af[4], gf[2], uf[2];
#pragma unroll
    for (int m = 0; m < 4; ++m) {
      int r = wr * 64 + m * 16 + fr;
      af[m] = __builtin_bit_cast(bf16x8, sA[b][r * 4 + (k8 ^ sw(r))]);
    }
#pragma unroll
    for (int n = 0; n < 2; ++n) {
      int r = wc * 32 + n * 16 + fr;
      gf[n] = __builtin_bit_cast(bf16x8, sG[b][r * 4 + (k8 ^ sw(r))]);
      uf[n] = __builtin_bit_cast(bf16x8, sU[b][r * 4 + (k8 ^ sw(r))]);
    }
#pragma unroll
    for (int m = 0; m < 4; ++m)
#pragma unroll
      for (int n = 0; n < 2; ++n) {
        accg[m][n] = __builtin_amdgcn_mfma_f32_16x16x32_bf16(af[m], gf[n], accg[m][n], 0, 0, 0);
        accu[m][n] = __builtin_amdgcn_mfma_f32_16x16x32_bf16(af[m], uf[n], accu[m][n], 0, 0, 0);
      }
  };

  const int KT = H_ / 32;  // 64
  loadNext();              // kt=0
  stage(0);
  loadNext();              // kt=1 in flight
  __syncthreads();
  int cur = 0;
  for (int kt = 0; kt < KT; ++kt) {
    compute(cur);
    if (kt + 1 < KT) {
      stage(cur ^ 1);
      if (kt + 2 < KT) loadNext();  // issue BEFORE barrier (R9 schedule)
      __syncthreads();
      cur ^= 1;
    }
  }

  // epilogue: h = ew * silu(g)*u, bf16, masked to valid rows
#pragma unroll
  for (int m = 0; m < 4; ++m)
#pragma unroll
    for (int r = 0; r < 4; ++r) {
      int rit = wr * 64 + m * 16 + k8 * 4 + r;
      if (r0 + rit < cnt) {
        float wgt = ew[s * T_ + r0 + rit];
        unsigned short* hrow = h + (size_t)(hrow0 + rit) * I_ + n0 + wc * 32;
#pragma unroll
        for (int n = 0; n < 2; ++n) {
          float g = accg[m][n][r], uv = accu[m][n][r];
          float hv = g / (1.f + expf(-g)) * uv * wgt;
          hrow[n * 16 + fr] = f2bf(hv);
        }
      }
    }
}

// -------- down GEMM: y[srow] = h . wd^T (plain stores) or atomic to out ----
// == R18 verbatim == A: tri-buffered DMA; B: reg+cvt dbuf; counted vmcnt.
__global__ __launch_bounds__(512, 4) void k_down(
    const unsigned short* __restrict__ h,
    const float* __restrict__ wd_all, const float* __restrict__ sd_all,
    const int* __restrict__ elist,
    const int* __restrict__ ecnt, const int* __restrict__ sbase,
    float* __restrict__ y, int use_y,
    float* __restrict__ out) {
  const int s = blockIdx.z;
  const int cnt = ecnt[s];
  const int r0 = blockIdx.y * 256;
  if (r0 >= cnt) return;
  const int n0 = blockIdx.x * 128;
  const float* bw = (s < E_) ? wd_all + (size_t)s * H_ * I_
                             : sd_all + (size_t)(s - E_) * H_ * I_;
  const int hrow0 = sbase[s] + r0;

  __shared__ u32x4 sA[3][1024];   // 256 rows x 4 chunks, tri (48KB)
  __shared__ u32x4 sB[2][512];    // 128 rows x 4 chunks, dbuf (16KB)

  const int tid = threadIdx.x;
  const int wv = tid >> 6, lane = tid & 63;
  const int wr = wv >> 1, wc = wv & 1;
  const int fr = lane & 15, k8 = lane >> 4;

  const int arow0 = wv * 32 + (lane >> 2);
  const int arow1 = arow0 + 16;
  const unsigned short* aSrc0 =
      h + (size_t)(hrow0 + arow0) * I_ + (((lane & 3) ^ sw(arow0)) * 8);
  const unsigned short* aSrc1 =
      h + (size_t)(hrow0 + arow1) * I_ + (((lane & 3) ^ sw(arow1)) * 8);

  const int brr = tid >> 2, cb = tid & 3;
  const float* bp = bw + (size_t)(n0 + brr) * I_ + cb * 8;
  f32x4 rb0, rb1;

  f32x4 acc[4][4];
#pragma unroll
  for (int m = 0; m < 4; ++m)
#pragma unroll
    for (int n = 0; n < 4; ++n) acc[m][n] = (f32x4){0.f, 0.f, 0.f, 0.f};

  auto dmaA = [&](int b, int kt) {
    load_lds16(aSrc0 + kt * 32, &sA[b][wv * 128]);
    load_lds16(aSrc1 + kt * 32, &sA[b][wv * 128 + 64]);
  };
  auto loadB = [&]() {
    rb0 = *(const f32x4*)bp; rb1 = *(const f32x4*)(bp + 4); bp += 32;
  };
  auto stageB = [&](int b) {
    u32x2 lo = cvt4(rb0), hi = cvt4(rb1);
    u32x4 q; q[0] = lo[0]; q[1] = lo[1]; q[2] = hi[0]; q[3] = hi[1];
    sB[b][brr * 4 + (cb ^ sw(brr))] = q;
  };
  auto compute = [&](int a, int b) {
    bf16x8 af[4], bf[4];
#pragma unroll
    for (int m = 0; m < 4; ++m) {
      int r = wr * 64 + m * 16 + fr;
      af[m] = __builtin_bit_cast(bf16x8, sA[a][r * 4 + (k8 ^ sw(r))]);
    }
#pragma unroll
    for (int n = 0; n < 4; ++n) {
      int r = wc * 64 + n * 16 + fr;
      bf[n] = __builtin_bit_cast(bf16x8, sB[b][r * 4 + (k8 ^ sw(r))]);
    }
#pragma unroll
    for (int m = 0; m < 4; ++m)
#pragma unroll
      for (int n = 0; n < 4; ++n)
        acc[m][n] = __builtin_amdgcn_mfma_f32_16x16x32_bf16(af[m], bf[n], acc[m][n], 0, 0, 0);
  };

  const int KT = I_ / 32;  // 160
  loadB();
  dmaA(0, 0);
  stageB(0);
  loadB();
  dmaA(1, 1);
  PIPE_SYNC(4);
  int aCur = 0, bCur = 0;
  for (int kt = 0; kt < KT; ++kt) {
    compute(aCur, bCur);
    if (kt + 1 < KT) {
      stageB(bCur ^ 1);
      if (kt + 2 < KT) {
        int nx = aCur + 2; if (nx >= 3) nx -= 3;
        dmaA(nx, kt + 2);
        loadB();
        PIPE_SYNC(4);
      } else {
        PIPE_SYNC(0);
      }
      aCur = (aCur == 2) ? 0 : aCur + 1;
      bCur ^= 1;
    }
  }

  if (use_y) {
#pragma unroll
    for (int m = 0; m < 4; ++m)
#pragma unroll
      for (int r = 0; r < 4; ++r) {
        int rit = wr * 64 + m * 16 + k8 * 4 + r;
        float* yrow = y + (size_t)(hrow0 + rit) * H_ + n0 + wc * 64 + fr;
#pragma unroll
        for (int n = 0; n < 4; ++n) yrow[n * 16] = acc[m][n][r];
      }
  } else {
    const int* lst = elist + s * T_;
#pragma unroll
    for (int m = 0; m < 4; ++m)
#pragma unroll
      for (int r = 0; r < 4; ++r) {
        int rit = wr * 64 + m * 16 + k8 * 4 + r;
        if (r0 + rit < cnt) {
          int t = lst[r0 + rit];
          float* orow = out + (size_t)t * H_ + n0 + wc * 64 + fr;
#pragma unroll
          for (int n = 0; n < 4; ++n) atomicAdd(orow + n * 16, acc[m][n][r]);
        }
      }
  }
}

// -------- combine: out[t] = y[routed0] + y[routed1] + y[shared0] + y[shared1]
__global__ __launch_bounds__(256) void k_combine(
    const float* __restrict__ y, const int* __restrict__ tki,
    const int* __restrict__ ipos, const int* __restrict__ sbase,
    float* __restrict__ out) {
  const int t = blockIdx.x;
  const int c = threadIdx.x * 8;
  const size_t r0 = (size_t)(sbase[tki[2 * t]] + ipos[2 * t]) * H_ + c;
  const size_t r1 = (size_t)(sbase[tki[2 * t + 1]] + ipos[2 * t + 1]) * H_ + c;
  const size_t r2 = (size_t)(sbase[8] + t) * H_ + c;
  const size_t r3 = (size_t)(sbase[9] + t) * H_ + c;
  f32x4 a0 = *(const f32x4*)(y + r0), b0 = *(const f32x4*)(y + r0 + 4);
  f32x4 a1 = *(const f32x4*)(y + r1), b1 = *(const f32x4*)(y + r1 + 4);
  f32x4 a2 = *(const f32x4*)(y + r2), b2 = *(const f32x4*)(y + r2 + 4);
  f32x4 a3 = *(const f32x4*)(y + r3), b3 = *(const f32x4*)(y + r3 + 4);
  f32x4 sa = (a0 + a1) + (a2 + a3);
  f32x4 sb = (b0 + b1) + (b2 + b3);
  float* o = out + (size_t)t * H_ + c;
  *(f32x4*)o = sa;
  *(f32x4*)(o + 4) = sb;
}

extern "C" void kernel_launch(void* const* d_in, const int* in_sizes, int n_in,
                              void* d_out, int out_size, void* d_ws, size_t ws_size,
                              hipStream_t stream) {
  const float* x  = (const float*)d_in[0];
  const float* wr = (const float*)d_in[1];
  const float* wg = (const float*)d_in[2];
  const float* wu = (const float*)d_in[3];
  const float* wd = (const float*)d_in[4];
  const float* sg = (const float*)d_in[5];
  const float* su = (const float*)d_in[6];
  const float* sd = (const float*)d_in[7];
  float* out = (float*)d_out;
  char* ws = (char*)d_ws;

  // workspace layout
  int*   tki   = (int*)(ws);                 // T*2 ints
  float* tkw   = (float*)(ws + 16384);       // T*2 floats
  int*   elist = (int*)(ws + 32768);         // NSLOT*T ints
  float* ew    = (float*)(ws + 114688);      // NSLOT*T floats
  int*   ecnt  = (int*)(ws + 196608);        // NSLOT ints
  int*   sbase = (int*)(ws + 196864);        // NSLOT ints
  int*   ipos  = (int*)(ws + 197632);        // T*2 ints
  unsigned short* xb = (unsigned short*)(ws + 262144);            // 8.4 MB
  unsigned short* h  = (unsigned short*)(ws + 262144 + 8388608);  // <=10496 rows x I bf16 (107.5 MB)
  float* y = (float*)(ws + 262144 + 8388608 + 107479040);         // <=10496 rows x H fp32 (86 MB)
  const size_t ws_need_y = 262144ull + 8388608ull + 107479040ull + 85983232ull;
  const int use_y = (ws_size >= ws_need_y) ? 1 : 0;

  k_castx<<<T_ * H_ / (256 * 8), 256, 0, stream>>>(x, xb);
  k_router<<<T_, 64, 0, stream>>>(x, wr, tki, tkw);
  k_lists<<<NSLOT, 64, 0, stream>>>(tki, tkw, elist, ew, ecnt, ipos);
  k_bases<<<1, 1, 0, stream>>>(ecnt, sbase);
  k_gateup<<<dim3(I_ / 128, T_ / 256, NSLOT), 1024, 0, stream>>>(
      xb, wg, wu, sg, su, elist, ew, ecnt, sbase, h);
  if (!use_y) hipMemsetAsync(out, 0, (size_t)T_ * H_ * sizeof(float), stream);
  k_down<<<dim3(H_ / 128, T_ / 256, NSLOT), 512, 0, stream>>>(
      h, wd, sd, elist, ecnt, sbase, y, use_y, out);
  if (use_y)
    k_combine<<<T_, 256, 0, stream>>>(y, tki, ipos, sbase, out);
}